// Round 2
// baseline (200.808 us; speedup 1.0000x reference)
//
#include <hip/hip_runtime.h>
#include <hip/hip_bf16.h>

#define B_SZ     32
#define K_UP     64
#define K_DOWN   192
#define D_DIM    768
#define S_UP     24576
#define C_CONN   256
#define NCOL     (B_SZ * K_UP)     // 2048 gathered columns
#define BM_WORDS (S_UP / 32)       // 768 u32 = 3 KB presence bitmap

#define KDB      8                 // kd per K2 block (amortize bitmap/up_idx setup)
#define NGRP     (K_DOWN / KDB)    // 24 groups per batch
#define MK       64                // match cap per kd; E=0.5, Binomial tail -> astronomically safe

// K1 tiling: stream the whole up_decoder sequentially, extract needed cols.
#define CCH      512               // cols per tile
#define RCH      16                // rows per tile
#define NCH_C    (S_UP / CCH)      // 48
#define NCH_R    (D_DIM / RCH)     // 48
#define SLOTS    192               // bucket capacity; E[hits]=42.7, sigma=6.4 -> +23 sigma

// ---------------------------------------------------------------------------
// K1: sequential-scan gather. Change this round: issue all 8 tile float4
// loads to registers BEFORE phase A (they're independent), so the 2048-index
// scan latency hides under the 32KB HBM fetch instead of serializing with it.
// ---------------------------------------------------------------------------
__global__ __launch_bounds__(256) void gather_up_cols_scan(
    const float* __restrict__ up_decoder,   // [D, S_UP]
    const int*   __restrict__ up_idx_flat,  // [NCOL]
    float*       __restrict__ ws_up)        // [NCOL, D_DIM]
{
    const int tid = threadIdx.x;
    const int c0  = blockIdx.x * CCH;       // 0..47 col chunks
    const int d0  = blockIdx.y * RCH;       // 0..47 row chunks

    __shared__ float tile[RCH][CCH + 4];    // +4 pad: phase-C bank spread, float4-aligned rows
    __shared__ int   s_j[SLOTS];
    __shared__ int   s_cc[SLOTS];
    __shared__ int   s_cnt;

    if (tid == 0) s_cnt = 0;
    __syncthreads();

    // ---- issue tile loads first (fills the HBM pipe) ----
    float4 v[8];
    #pragma unroll
    for (int k = 0; k < 8; ++k) {
        const int lin = k * 256 + tid;      // 0..2047 float4 slots
        const int r   = lin >> 7;           // 16 rows x 128 float4/row
        const int c4  = lin & 127;
        v[k] = *(const float4*)&up_decoder[(size_t)(d0 + r) * S_UP + c0 + c4 * 4];
    }

    // ---- phase A: bucket target columns falling in [c0, c0+CCH) ----
    // (runs under the latency of the loads above)
    for (int i = tid; i < NCOL; i += 256) {
        const int cc = up_idx_flat[i] - c0;
        if (cc >= 0 && cc < CCH) {
            int slot = atomicAdd(&s_cnt, 1);
            if (slot < SLOTS) { s_j[slot] = i; s_cc[slot] = cc; }
        }
    }

    // ---- phase B: land tile into LDS ----
    #pragma unroll
    for (int k = 0; k < 8; ++k) {
        const int lin = k * 256 + tid;
        const int r   = lin >> 7;
        const int c4  = lin & 127;
        *(float4*)&tile[r][c4 * 4] = v[k];
    }
    __syncthreads();

    int cnt = s_cnt; if (cnt > SLOTS) cnt = SLOTS;

    // ---- phase C: scatter matched cols; 4 lanes per slot, float4 per lane ----
    const int q = tid & 3;
    for (int s = tid >> 2; s < cnt; s += 64) {
        const int j  = s_j[s];
        const int cc = s_cc[s];
        float4 w = make_float4(tile[4 * q + 0][cc], tile[4 * q + 1][cc],
                               tile[4 * q + 2][cc], tile[4 * q + 3][cc]);
        *(float4*)&ws_up[(size_t)j * D_DIM + d0 + 4 * q] = w;   // 64B contiguous per slot
    }
}

// ---------------------------------------------------------------------------
// K2 (restructured): 8 kd per block.
//  - bitmap / up_indices / up_vals / b_dec setup amortized 8x (was per-kd)
//  - all 8 dj + conn rows + drows issued up front -> 8x memory parallelism
//    per latency window; the 8 match phases run barrier-free back to back.
//  - per-kd accumulate + dot reuse c0..c2 registers sequentially; one final
//    barrier for the cross-wave reduction of all 8 partials.
// ---------------------------------------------------------------------------
__global__ __launch_bounds__(256) void scae_pruned_contrib(
    const float* __restrict__ up_decoder,   // [D, S_UP]
    const float* __restrict__ ws_up,        // [NCOL, D_DIM] or nullptr
    const float* __restrict__ down_encoder, // [S_DOWN, D]
    const float* __restrict__ up_b_dec,     // [D]
    const float* __restrict__ up_vals,      // [B, K_UP]
    const int*   __restrict__ connections,  // [S_DOWN, C]
    const int*   __restrict__ up_indices,   // [B, K_UP]
    const int*   __restrict__ down_indices, // [B, K_DOWN]
    float*       __restrict__ out,          // [B, K_DOWN]
    const int                 use_ws)
{
    const int tid = threadIdx.x;
    const int blk = blockIdx.x;
    const int b   = blk / NGRP;
    const int g   = blk - b * NGRP;
    const int kd0 = g * KDB;

    __shared__ int      s_upidx[K_UP];
    __shared__ float    s_upvals[K_UP];
    __shared__ unsigned s_bm[BM_WORDS];
    __shared__ int      s_ku[KDB][MK];
    __shared__ float    s_coef[KDB][MK];
    __shared__ int      s_nm[KDB];
    __shared__ float    s_red[KDB][4];

    // ---- per-kd indices (uniform scalar loads, issue immediately) ----
    int dj[KDB];
    #pragma unroll
    for (int k = 0; k < KDB; ++k)
        dj[k] = down_indices[b * K_DOWN + kd0 + k];

    // ---- issue every independent global load before the first barrier ----
    int vv[KDB];
    float dr0[KDB], dr1[KDB], dr2[KDB];
    #pragma unroll
    for (int k = 0; k < KDB; ++k) {
        vv[k] = connections[(size_t)dj[k] * C_CONN + tid];       // 1 KB coalesced
        const float* drow = down_encoder + (size_t)dj[k] * D_DIM;
        dr0[k] = drow[tid];                                      // 3 KB coalesced
        dr1[k] = drow[tid + 256];
        dr2[k] = drow[tid + 512];
    }

    const float bd0 = up_b_dec[tid];                             // L2-resident
    const float bd1 = up_b_dec[tid + 256];
    const float bd2 = up_b_dec[tid + 512];

    int   ui = 0;
    float uv = 0.f;
    if (tid < K_UP) {
        ui = up_indices[b * K_UP + tid];
        uv = up_vals[b * K_UP + tid];
    }

    // ---- bitmap + bookkeeping init (LDS writes overlap the loads above) ----
    #pragma unroll
    for (int w = 0; w < BM_WORDS / 256; ++w) s_bm[tid + 256 * w] = 0u;
    if (tid < KDB) s_nm[tid] = 0;
    if (tid < K_UP) { s_upidx[tid] = ui; s_upvals[tid] = uv; }
    __syncthreads();

    if (tid < K_UP) atomicOr(&s_bm[ui >> 5], 1u << (ui & 31));
    __syncthreads();

    // ---- match phases: O(1) bitmap test per conn entry; barrier-free ----
    #pragma unroll
    for (int k = 0; k < KDB; ++k) {
        const int v = vv[k];
        if (v >= 0 && ((s_bm[v >> 5] >> (v & 31)) & 1u)) {
            for (int ku = 0; ku < K_UP; ++ku) {
                if (s_upidx[ku] == v) {
                    int slot = atomicAdd(&s_nm[k], 1);
                    if (slot < MK) {
                        s_ku[k][slot]   = ku;
                        s_coef[k][slot] = s_upvals[ku];
                    }
                }
            }
        }
    }
    __syncthreads();

    // ---- per-kd: combined vector, dot with drow, wave-level reduce ----
    float p[KDB];
    #pragma unroll
    for (int k = 0; k < KDB; ++k) {
        int nm = s_nm[k];
        if (nm > MK) nm = MK;

        float c0 = bd0, c1 = bd1, c2 = bd2;
        for (int m = 0; m < nm; ++m) {
            const float coef = s_coef[k][m];
            const int   ku   = s_ku[k][m];
            if (use_ws) {
                const float* colp = ws_up + (size_t)(b * K_UP + ku) * D_DIM;
                c0 += coef * colp[tid];
                c1 += coef * colp[tid + 256];
                c2 += coef * colp[tid + 512];
            } else {
                const int col = s_upidx[ku];
                c0 += coef * up_decoder[(size_t)(tid      ) * S_UP + col];
                c1 += coef * up_decoder[(size_t)(tid + 256) * S_UP + col];
                c2 += coef * up_decoder[(size_t)(tid + 512) * S_UP + col];
            }
        }
        p[k] = c0 * dr0[k] + c1 * dr1[k] + c2 * dr2[k];
    }

    const int wave = tid >> 6;
    const int lane = tid & 63;
    #pragma unroll
    for (int k = 0; k < KDB; ++k) {
        float r = p[k];
        for (int off = 32; off > 0; off >>= 1)
            r += __shfl_down(r, off, 64);
        if (lane == 0) s_red[k][wave] = r;
    }
    __syncthreads();

    if (tid < KDB) {
        out[b * K_DOWN + kd0 + tid] =
            s_red[tid][0] + s_red[tid][1] + s_red[tid][2] + s_red[tid][3];
    }
}

extern "C" void kernel_launch(void* const* d_in, const int* in_sizes, int n_in,
                              void* d_out, int out_size, void* d_ws, size_t ws_size,
                              hipStream_t stream) {
    const float* up_decoder   = (const float*)d_in[0];
    const float* down_encoder = (const float*)d_in[1];
    const float* up_b_dec     = (const float*)d_in[2];
    const float* up_vals      = (const float*)d_in[3];
    const int*   connections  = (const int*)d_in[4];
    const int*   up_indices   = (const int*)d_in[5];
    const int*   down_indices = (const int*)d_in[6];
    float*       out          = (float*)d_out;
    float*       ws_up        = (float*)d_ws;

    const size_t ws_needed = (size_t)NCOL * D_DIM * sizeof(float);  // 6.29 MB
    const int    use_ws    = (d_ws != nullptr && ws_size >= ws_needed) ? 1 : 0;

    if (use_ws) {
        gather_up_cols_scan<<<dim3(NCH_C, NCH_R), dim3(256), 0, stream>>>(
            up_decoder, up_indices, ws_up);
    }

    scae_pruned_contrib<<<dim3(B_SZ * (K_DOWN / KDB)), dim3(256), 0, stream>>>(
        up_decoder, ws_up, down_encoder, up_b_dec, up_vals,
        connections, up_indices, down_indices, out, use_ws);
}

// Round 3
// 186.690 us; speedup vs baseline: 1.0756x; 1.0756x over previous
//
#include <hip/hip_runtime.h>
#include <hip/hip_bf16.h>

#define B_SZ     32
#define K_UP     64
#define K_DOWN   192
#define D_DIM    768
#define S_UP     24576
#define C_CONN   256
#define NCOL     (B_SZ * K_UP)     // 2048 gathered columns
#define MAXM     512
#define BM_WORDS (S_UP / 32)       // 768 u32 = 3 KB presence bitmap

// K1 tiling: stream the whole up_decoder sequentially, extract needed cols.
#define CCH      512               // cols per tile
#define RCH      16                // rows per tile
#define NCH_C    (S_UP / CCH)      // 48
#define NCH_R    (D_DIM / RCH)     // 48
#define SLOTS    192               // bucket capacity; E[hits]=42.7, sigma=6.4 -> +23 sigma

// ---------------------------------------------------------------------------
// K1: sequential-scan gather. This round's only change vs the Round-1 winner:
// issue all 8 tile float4 loads to registers BEFORE the phase-A index scan
// (they're independent), so the 2048-index scan runs under the 32KB HBM
// fetch latency instead of in front of it.
// ---------------------------------------------------------------------------
__global__ __launch_bounds__(256) void gather_up_cols_scan(
    const float* __restrict__ up_decoder,   // [D, S_UP]
    const int*   __restrict__ up_idx_flat,  // [NCOL]
    float*       __restrict__ ws_up)        // [NCOL, D_DIM]
{
    const int tid = threadIdx.x;
    const int c0  = blockIdx.x * CCH;       // 0..47 col chunks
    const int d0  = blockIdx.y * RCH;       // 0..47 row chunks

    __shared__ float tile[RCH][CCH + 4];    // +4 pad: phase-C bank spread, float4-aligned rows
    __shared__ int   s_j[SLOTS];
    __shared__ int   s_cc[SLOTS];
    __shared__ int   s_cnt;

    if (tid == 0) s_cnt = 0;
    __syncthreads();

    // ---- issue tile loads first (fills the HBM pipe) ----
    float4 v[8];
    #pragma unroll
    for (int k = 0; k < 8; ++k) {
        const int lin = k * 256 + tid;      // 0..2047 float4 slots
        const int r   = lin >> 7;           // 16 rows x 128 float4/row
        const int c4  = lin & 127;
        v[k] = *(const float4*)&up_decoder[(size_t)(d0 + r) * S_UP + c0 + c4 * 4];
    }

    // ---- phase A: bucket target columns falling in [c0, c0+CCH) ----
    // (runs under the latency of the loads above)
    for (int i = tid; i < NCOL; i += 256) {
        const int cc = up_idx_flat[i] - c0;
        if (cc >= 0 && cc < CCH) {
            int slot = atomicAdd(&s_cnt, 1);
            if (slot < SLOTS) { s_j[slot] = i; s_cc[slot] = cc; }
        }
    }

    // ---- phase B: land tile into LDS ----
    #pragma unroll
    for (int k = 0; k < 8; ++k) {
        const int lin = k * 256 + tid;
        const int r   = lin >> 7;
        const int c4  = lin & 127;
        *(float4*)&tile[r][c4 * 4] = v[k];
    }
    __syncthreads();

    int cnt = s_cnt; if (cnt > SLOTS) cnt = SLOTS;

    // ---- phase C: scatter matched cols; 4 lanes per slot, float4 per lane ----
    const int q = tid & 3;
    for (int s = tid >> 2; s < cnt; s += 64) {
        const int j  = s_j[s];
        const int cc = s_cc[s];
        float4 w = make_float4(tile[4 * q + 0][cc], tile[4 * q + 1][cc],
                               tile[4 * q + 2][cc], tile[4 * q + 3][cc]);
        *(float4*)&ws_up[(size_t)j * D_DIM + d0 + 4 * q] = w;   // 64B contiguous per slot
    }
}

// ---------------------------------------------------------------------------
// K2: EXACT revert to the Round-1 winner. One block per output element
// (6144 blocks -> 8 resident blocks/CU, full TLP), hoisted independent
// loads, 3KB presence-bitmap match with rare 64-scan fallback.
// Round-2 post-mortem: batching 8 kd/block cut the grid to 3 blocks/CU and
// added ~40 VGPRs of per-kd state -> latency-bound kernel lost its TLP.
// ---------------------------------------------------------------------------
__global__ __launch_bounds__(256) void scae_pruned_contrib(
    const float* __restrict__ up_decoder,   // [D, S_UP]
    const float* __restrict__ ws_up,        // [NCOL, D_DIM] or nullptr
    const float* __restrict__ down_encoder, // [S_DOWN, D]
    const float* __restrict__ up_b_dec,     // [D]
    const float* __restrict__ up_vals,      // [B, K_UP]
    const int*   __restrict__ connections,  // [S_DOWN, C]
    const int*   __restrict__ up_indices,   // [B, K_UP]
    const int*   __restrict__ down_indices, // [B, K_DOWN]
    float*       __restrict__ out,          // [B, K_DOWN]
    const int                 use_ws)
{
    const int tid = threadIdx.x;
    const int blk = blockIdx.x;
    const int b   = blk / K_DOWN;
    const int kd  = blk - b * K_DOWN;

    __shared__ int      s_upidx[K_UP];
    __shared__ float    s_upvals[K_UP];
    __shared__ unsigned s_bm[BM_WORDS];
    __shared__ int      s_ku[MAXM];
    __shared__ float    s_coef[MAXM];
    __shared__ int      s_nm;
    __shared__ float    s_red[4];

    // ---- issue every independent global load before the first barrier ----
    const int dj = down_indices[b * K_DOWN + kd];              // broadcast, 1 line
    const int v  = connections[(size_t)dj * C_CONN + tid];     // 1 KB coalesced

    const float* drow = down_encoder + (size_t)dj * D_DIM;
    const float dr0 = drow[tid];                               // 3 KB coalesced
    const float dr1 = drow[tid + 256];
    const float dr2 = drow[tid + 512];

    float c0 = up_b_dec[tid];                                  // L2-resident
    float c1 = up_b_dec[tid + 256];
    float c2 = up_b_dec[tid + 512];

    int   ui = 0;
    float uv = 0.f;
    if (tid < K_UP) {
        ui = up_indices[b * K_UP + tid];
        uv = up_vals[b * K_UP + tid];
    }

    // ---- bitmap + bookkeeping init (LDS writes overlap the loads above) ----
    #pragma unroll
    for (int w = 0; w < BM_WORDS / 256; ++w) s_bm[tid + 256 * w] = 0u;
    if (tid == 0) s_nm = 0;
    if (tid < K_UP) { s_upidx[tid] = ui; s_upvals[tid] = uv; }
    __syncthreads();

    if (tid < K_UP) atomicOr(&s_bm[ui >> 5], 1u << (ui & 31));
    __syncthreads();

    // ---- match phase: O(1) bitmap test; rare hits do the 64-scan ----
    if (v >= 0 && ((s_bm[v >> 5] >> (v & 31)) & 1u)) {
        for (int ku = 0; ku < K_UP; ++ku) {
            if (s_upidx[ku] == v) {
                int slot = atomicAdd(&s_nm, 1);
                if (slot < MAXM) {
                    s_ku[slot]   = ku;
                    s_coef[slot] = s_upvals[ku];
                }
            }
        }
    }
    __syncthreads();
    int nm = s_nm;
    if (nm > MAXM) nm = MAXM;

    // ---- combined vector: b_dec + sum of matched coef * column ----
    for (int m = 0; m < nm; ++m) {
        const float coef = s_coef[m];
        const int   ku   = s_ku[m];
        if (use_ws) {
            const float* colp = ws_up + (size_t)(b * K_UP + ku) * D_DIM;
            c0 += coef * colp[tid];
            c1 += coef * colp[tid + 256];
            c2 += coef * colp[tid + 512];
        } else {
            const int col = s_upidx[ku];
            c0 += coef * up_decoder[(size_t)(tid      ) * S_UP + col];
            c1 += coef * up_decoder[(size_t)(tid + 256) * S_UP + col];
            c2 += coef * up_decoder[(size_t)(tid + 512) * S_UP + col];
        }
    }

    // ---- dot with downstream encoder row (registers, loaded up front) ----
    float partial = c0 * dr0 + c1 * dr1 + c2 * dr2;

    // ---- block reduction ----
    for (int off = 32; off > 0; off >>= 1)
        partial += __shfl_down(partial, off, 64);
    const int wave = tid >> 6;
    const int lane = tid & 63;
    if (lane == 0) s_red[wave] = partial;
    __syncthreads();
    if (tid == 0) {
        out[blk] = s_red[0] + s_red[1] + s_red[2] + s_red[3];
    }
}

extern "C" void kernel_launch(void* const* d_in, const int* in_sizes, int n_in,
                              void* d_out, int out_size, void* d_ws, size_t ws_size,
                              hipStream_t stream) {
    const float* up_decoder   = (const float*)d_in[0];
    const float* down_encoder = (const float*)d_in[1];
    const float* up_b_dec     = (const float*)d_in[2];
    const float* up_vals      = (const float*)d_in[3];
    const int*   connections  = (const int*)d_in[4];
    const int*   up_indices   = (const int*)d_in[5];
    const int*   down_indices = (const int*)d_in[6];
    float*       out          = (float*)d_out;
    float*       ws_up        = (float*)d_ws;

    const size_t ws_needed = (size_t)NCOL * D_DIM * sizeof(float);  // 6.29 MB
    const int    use_ws    = (d_ws != nullptr && ws_size >= ws_needed) ? 1 : 0;

    if (use_ws) {
        gather_up_cols_scan<<<dim3(NCH_C, NCH_R), dim3(256), 0, stream>>>(
            up_decoder, up_indices, ws_up);
    }

    scae_pruned_contrib<<<dim3(B_SZ * K_DOWN), dim3(256), 0, stream>>>(
        up_decoder, ws_up, down_encoder, up_b_dec, up_vals,
        connections, up_indices, down_indices, out, use_ws);
}